// Round 4
// baseline (703.789 us; speedup 1.0000x reference)
//
#include <hip/hip_runtime.h>
#include <math.h>

// Problem: x shape (B=4, C=8, D=16, H=256, W=256), 3x3x3 window, stride 1, pad 1.
// exp(x) direct (no channel-max): soft-argmax ratios are shift-invariant, inputs
// N(0,1) -> exp range ~[4e-3, 4e2]; validated correct in rounds 2-3.
// Nontemporal stores: proven +90us faster than cached (round 3 differential).
#define BC 32
#define DD 16
#define HH 256
#define WW 256
#define PLANE (HH * WW)              // 65536
#define CH_ELEMS (DD * PLANE)        // 1048576
#define COORD_ELEMS (BC * 3 * CH_ELEMS)  // 100663296

// Tile: 8 h x 128 w (was 16x64). Each wave's nt store instr now covers
// 2 x 512 B contiguous segments (was 4 x 256 B) -- store-width differential.
#define TILE_H 8
#define TILE_W 128
#define NROWS 10                     // TILE_H + 2 halo
#define NCOLS 130                    // TILE_W + 2 halo
#define TS 132                       // LDS row stride (130 used + 2 pad, 16B-aligned)
#define SELEMS (NROWS * NCOLS)       // 1300 staged elems per slice

typedef float vf4 __attribute__((ext_vector_type(4)));

__global__ __launch_bounds__(256) void csam3d_main(const float* __restrict__ xin_all,
                                                   float* __restrict__ out) {
    const int ch = blockIdx.z;
    const int h0 = blockIdx.y * TILE_H;
    const int w0 = blockIdx.x * TILE_W;
    const int tid = threadIdx.x;
    const float* __restrict__ xin = xin_all + (size_t)ch * CH_ELEMS;

    float* __restrict__ outz = out + (size_t)(ch * 3 + 0) * CH_ELEMS;
    float* __restrict__ outx = out + (size_t)(ch * 3 + 1) * CH_ELEMS;
    float* __restrict__ outy = out + (size_t)(ch * 3 + 2) * CH_ELEMS;
    float* __restrict__ outv = out + COORD_ELEMS + (size_t)ch * CH_ELEMS;

    __shared__ __align__(16) float eS[2][NROWS * TS];  // exp(x), zero-padded halo
    __shared__ __align__(16) float vS[2][NROWS * TS];  // e * x

    const int hl = tid >> 5;          // 0..7
    const int wb = (tid & 31) << 2;   // 0,4,...,124

    // 3-slot ring of per-slice 2D window stats, 4 w-outputs each
    float s2[3][4], mx2[3][4], my2[3][4], sv2[3][4];

// Stage slice I (input depth din = I-1; out-of-range depth -> zeros) into buffer I&1.
#define STAGE(I) do {                                                         \
    const int din_ = (I) - 1;                                                 \
    float* eb_ = eS[(I) & 1];                                                 \
    float* vb_ = vS[(I) & 1];                                                 \
    if (din_ < 0 || din_ >= DD) {                                             \
        for (int s5 = tid; s5 < NROWS * TS; s5 += 256) { eb_[s5] = 0.f; vb_[s5] = 0.f; } \
    } else {                                                                  \
        const float* xp_ = xin + (size_t)din_ * PLANE;                        \
        _Pragma("unroll")                                                     \
        for (int it = 0; it < 6; ++it) {                                      \
            int s5 = tid + it * 256;                                          \
            if (s5 < SELEMS) {                                                \
                int lh = s5 / NCOLS;                                          \
                int lw = s5 - lh * NCOLS;                                     \
                int gh = h0 + lh - 1;                                         \
                int gw = w0 + lw - 1;                                         \
                float ev = 0.f, vv = 0.f;                                     \
                if ((unsigned)gh < (unsigned)HH && (unsigned)gw < (unsigned)WW) { \
                    float xv = xp_[gh * WW + gw];                             \
                    ev = __expf(xv);                                          \
                    vv = ev * xv;                                             \
                }                                                             \
                eb_[lh * TS + lw] = ev;                                       \
                vb_[lh * TS + lw] = vv;                                       \
            }                                                                 \
        }                                                                     \
    }                                                                         \
} while (0)

#define LDROW(PTR) do {                                                       \
    float4 a_ = *(const float4*)(PTR);                                        \
    float2 b_ = *(const float2*)((PTR) + 4);                                  \
    v0 = a_.x; v1 = a_.y; v2 = a_.z; v3 = a_.w; v4 = b_.x; v5 = b_.y;         \
} while (0)

// Compute 2D (h,w) window stats for slice I into ring slot SC.
#define CSLICE(I, SC) do {                                                    \
    const float* eb_ = eS[(I) & 1] + hl * TS + wb;                            \
    const float* vb_ = vS[(I) & 1] + hl * TS + wb;                            \
    float v0, v1, v2, v3, v4, v5;                                             \
    LDROW(eb_);                                                               \
    float c0 = v0, c1 = v1, c2 = v2, c3 = v3, c4 = v4, c5 = v5;               \
    float d0 = -v0, d1 = -v1, d2 = -v2, d3 = -v3, d4 = -v4, d5 = -v5;         \
    LDROW(eb_ + TS);                                                          \
    c0 += v0; c1 += v1; c2 += v2; c3 += v3; c4 += v4; c5 += v5;               \
    LDROW(eb_ + 2 * TS);                                                      \
    c0 += v0; c1 += v1; c2 += v2; c3 += v3; c4 += v4; c5 += v5;               \
    d0 += v0; d1 += v1; d2 += v2; d3 += v3; d4 += v4; d5 += v5;               \
    LDROW(vb_);                                                               \
    float g0 = v0, g1 = v1, g2 = v2, g3 = v3, g4 = v4, g5 = v5;               \
    LDROW(vb_ + TS);                                                          \
    g0 += v0; g1 += v1; g2 += v2; g3 += v3; g4 += v4; g5 += v5;               \
    LDROW(vb_ + 2 * TS);                                                      \
    g0 += v0; g1 += v1; g2 += v2; g3 += v3; g4 += v4; g5 += v5;               \
    s2[SC][0] = c0 + c1 + c2;  s2[SC][1] = c1 + c2 + c3;                      \
    s2[SC][2] = c2 + c3 + c4;  s2[SC][3] = c3 + c4 + c5;                      \
    mx2[SC][0] = c2 - c0; mx2[SC][1] = c3 - c1;                               \
    mx2[SC][2] = c4 - c2; mx2[SC][3] = c5 - c3;                               \
    my2[SC][0] = d0 + d1 + d2;  my2[SC][1] = d1 + d2 + d3;                    \
    my2[SC][2] = d2 + d3 + d4;  my2[SC][3] = d3 + d4 + d5;                    \
    sv2[SC][0] = g0 + g1 + g2;  sv2[SC][1] = g1 + g2 + g3;                    \
    sv2[SC][2] = g2 + g3 + g4;  sv2[SC][3] = g3 + g4 + g5;                    \
} while (0)

// Emit output depth dout = I-2 combining ring slots SA (d-1), SB (d), SC (d+1).
#define EMIT(I, SA, SB, SC) do {                                              \
    const int dout_ = (I) - 2;                                                \
    vf4 oz, ox, oy, ov;                                                       \
    _Pragma("unroll")                                                         \
    for (int k = 0; k < 4; ++k) {                                             \
        float S  = s2[SA][k] + s2[SB][k] + s2[SC][k];                         \
        float Mz = s2[SC][k] - s2[SA][k];                                     \
        float Mx = mx2[SA][k] + mx2[SB][k] + mx2[SC][k];                      \
        float My = my2[SA][k] + my2[SB][k] + my2[SC][k];                      \
        float Sv = sv2[SA][k] + sv2[SB][k] + sv2[SC][k];                      \
        float inv = __builtin_amdgcn_rcpf(S + 1e-8f);                         \
        oz[k] = Mz * inv + (float)dout_;                                      \
        ox[k] = Mx * inv + (float)(w0 + wb + k);                              \
        oy[k] = My * inv + (float)(h0 + hl);                                  \
        ov[k] = Sv * inv;                                                     \
    }                                                                         \
    size_t off_ = (size_t)dout_ * PLANE + (size_t)(h0 + hl) * WW + (w0 + wb); \
    __builtin_nontemporal_store(oz, (vf4*)(outz + off_));                     \
    __builtin_nontemporal_store(ox, (vf4*)(outx + off_));                     \
    __builtin_nontemporal_store(oy, (vf4*)(outy + off_));                     \
    __builtin_nontemporal_store(ov, (vf4*)(outv + off_));                     \
} while (0)

#define STEP(I, SC, SA, SB) do {                                              \
    STAGE(I);                                                                 \
    __syncthreads();                                                          \
    CSLICE(I, SC);                                                            \
    if ((I) >= 2) EMIT(I, SA, SB, SC);                                        \
} while (0)

    for (int ii = 0; ii < 18; ii += 3) {
        STEP(ii + 0, 0, 1, 2);
        STEP(ii + 1, 1, 2, 0);
        STEP(ii + 2, 2, 0, 1);
    }
}

extern "C" void kernel_launch(void* const* d_in, const int* in_sizes, int n_in,
                              void* d_out, int out_size, void* d_ws, size_t ws_size,
                              hipStream_t stream) {
    const float* x = (const float*)d_in[0];
    float* out = (float*)d_out;
    (void)d_ws; (void)ws_size;
    csam3d_main<<<dim3(WW / TILE_W, HH / TILE_H, 32), 256, 0, stream>>>(x, out);
}

// Round 5
// 637.029 us; speedup vs baseline: 1.1048x; 1.1048x over previous
//
#include <hip/hip_runtime.h>
#include <math.h>

// Problem: x shape (B=4, C=8, D=16, H=256, W=256), 3x3x3 window, stride 1, pad 1.
// Structure = proven 633us baseline (R0): chmax warming pass + 16hx64w tile +
// nontemporal stores + 1 barrier/step. The chmax pass is load-bearing BEYOND the
// max: it re-reads the input after the harness's 2GiB poison fill, so the main
// kernel's reads are Infinity-Cache hits and its HBM channel is a pure nt-write
// stream (rounds 2-4: removing it cost +50..90us). Differential this round:
// vectorized staging (dwordx4 + ds_write_b128) replacing scalar staging.
#define BC 32
#define DD 16
#define HH 256
#define WW 256
#define PLANE (HH * WW)              // 65536
#define CH_ELEMS (DD * PLANE)        // 1048576
#define COORD_ELEMS (BC * 3 * CH_ELEMS)  // 100663296

#define TSF 72                       // LDS row stride (18 quads; col c = gw-(w0-4))
#define NQ 18                        // float4 quads per staged row
#define NROWS 18                     // h halo rows
#define QUADS (NROWS * NQ)           // 324 quads per slice

typedef float vf4 __attribute__((ext_vector_type(4)));

// ---------------- Pass 1: per-channel max (also warms L3 for pass 2) ----------
__global__ __launch_bounds__(256) void chmax_part(const float* __restrict__ x,
                                                  float* __restrict__ part) {
    const int ch = blockIdx.y;
    const int tid = threadIdx.x;
    const float4* p4 = (const float4*)(x + (size_t)ch * CH_ELEMS) + (size_t)blockIdx.x * 4096;
    float m = -3.402823466e38f;
#pragma unroll
    for (int i = 0; i < 16; ++i) {
        float4 v = p4[tid + i * 256];
        m = fmaxf(m, fmaxf(fmaxf(v.x, v.y), fmaxf(v.z, v.w)));
    }
#pragma unroll
    for (int off = 32; off > 0; off >>= 1)
        m = fmaxf(m, __shfl_down(m, off, 64));
    __shared__ float sm[4];
    if ((tid & 63) == 0) sm[tid >> 6] = m;
    __syncthreads();
    if (tid == 0)
        part[ch * 64 + blockIdx.x] = fmaxf(fmaxf(sm[0], sm[1]), fmaxf(sm[2], sm[3]));
}

__global__ __launch_bounds__(64) void chmax_final(const float* __restrict__ part,
                                                  float* __restrict__ mx) {
    const int ch = blockIdx.x, tid = threadIdx.x;
    float m = part[ch * 64 + tid];
#pragma unroll
    for (int off = 32; off > 0; off >>= 1)
        m = fmaxf(m, __shfl_down(m, off, 64));
    if (tid == 0) mx[ch] = m;
}

// ---------------- Pass 2: fused conv-soft-argmax ----------------
// Block: 256 threads. Tile: 16 h x 64 w, full D loop, one channel (blockIdx.z).
// Thread (hl = tid>>4, wb = (tid&15)*4) owns 4 consecutive w outputs for all d.
__global__ __launch_bounds__(256) void csam3d_main(const float* __restrict__ xin_all,
                                                   const float* __restrict__ mx,
                                                   float* __restrict__ out) {
    const int ch = blockIdx.z;
    const int h0 = blockIdx.y * 16;
    const int w0 = blockIdx.x * 64;
    const int tid = threadIdx.x;
    const float cmax = mx[ch];
    const float* __restrict__ xin = xin_all + (size_t)ch * CH_ELEMS;

    float* __restrict__ outz = out + (size_t)(ch * 3 + 0) * CH_ELEMS;
    float* __restrict__ outx = out + (size_t)(ch * 3 + 1) * CH_ELEMS;
    float* __restrict__ outy = out + (size_t)(ch * 3 + 2) * CH_ELEMS;
    float* __restrict__ outv = out + COORD_ELEMS + (size_t)ch * CH_ELEMS;

    __shared__ __align__(16) float eS[2][NROWS * TSF];  // exp(x-cmax), zero halo
    __shared__ __align__(16) float vS[2][NROWS * TSF];  // e * x

    const int hl = tid >> 4;          // 0..15
    const int wb = (tid & 15) << 2;   // 0,4,...,60

    // ---- staging metadata, computed once: 324 f4 quads over 256 threads ----
    // Quad (row, c4): global col base gwb = w0-4+4*c4; LDS col 4*c4. Window reads
    // need cols 3..68 only, so cols 0..2 / 69..71 may hold garbage (never read).
    // Tile parity (w0 % 64 == 0) => every quad is fully valid or fully zero.
    int po[2], lo[2];
    bool lv[2];
#pragma unroll
    for (int it = 0; it < 2; ++it) {
        int slot = tid + it * 256;
        int row = slot / NQ;
        int c4 = slot - row * NQ;
        int gh = h0 + row - 1;
        int gwb = w0 - 4 + (c4 << 2);
        bool act = slot < QUADS;
        lv[it] = act && ((unsigned)gh < (unsigned)HH) && ((unsigned)gwb <= (unsigned)(WW - 4));
        po[it] = lv[it] ? (gh * WW + gwb) : 0;
        lo[it] = row * TSF + (c4 << 2);
    }

    // 3-slot ring of per-slice 2D window stats, 4 w-outputs each
    float s2[3][4], mx2[3][4], my2[3][4], sv2[3][4];

// Stage slice I (input depth din = I-1; OOR depth -> zero quads) into buffer I&1.
#define STAGE(I) do {                                                         \
    const int din_ = (I) - 1;                                                 \
    float* eb_ = eS[(I) & 1];                                                 \
    float* vb_ = vS[(I) & 1];                                                 \
    if (din_ < 0 || din_ >= DD) {                                             \
        _Pragma("unroll")                                                     \
        for (int it = 0; it < 2; ++it) {                                      \
            if (it == 0 || tid < QUADS - 256) {                               \
                *(vf4*)(eb_ + lo[it]) = (vf4){0.f, 0.f, 0.f, 0.f};            \
                *(vf4*)(vb_ + lo[it]) = (vf4){0.f, 0.f, 0.f, 0.f};            \
            }                                                                 \
        }                                                                     \
    } else {                                                                  \
        const float* xp_ = xin + (size_t)din_ * PLANE;                        \
        _Pragma("unroll")                                                     \
        for (int it = 0; it < 2; ++it) {                                      \
            if (it == 0 || tid < QUADS - 256) {                               \
                vf4 e4 = {0.f, 0.f, 0.f, 0.f}, v4 = {0.f, 0.f, 0.f, 0.f};    \
                if (lv[it]) {                                                 \
                    float4 xv_ = *(const float4*)(xp_ + po[it]);              \
                    float e0_ = __expf(xv_.x - cmax);                         \
                    float e1_ = __expf(xv_.y - cmax);                         \
                    float e2_ = __expf(xv_.z - cmax);                         \
                    float e3_ = __expf(xv_.w - cmax);                         \
                    e4 = (vf4){e0_, e1_, e2_, e3_};                           \
                    v4 = (vf4){e0_ * xv_.x, e1_ * xv_.y, e2_ * xv_.z, e3_ * xv_.w}; \
                }                                                             \
                *(vf4*)(eb_ + lo[it]) = e4;                                   \
                *(vf4*)(vb_ + lo[it]) = v4;                                   \
            }                                                                 \
        }                                                                     \
    }                                                                         \
} while (0)

// Load window cols [wb+3, wb+8] from the c-layout via aligned b64 + b128 + b64.
// PTR points at col wb (16B-aligned).
#define LDROW(PTR) do {                                                       \
    float2 a_ = *(const float2*)((PTR) + 2);                                  \
    float4 m_ = *(const float4*)((PTR) + 4);                                  \
    float2 b_ = *(const float2*)((PTR) + 8);                                  \
    v0 = a_.y; v1 = m_.x; v2 = m_.y; v3 = m_.z; v4 = m_.w; v5 = b_.x;         \
} while (0)

// Compute 2D (h,w) window stats for slice I into ring slot SC.
#define CSLICE(I, SC) do {                                                    \
    const float* eb_ = eS[(I) & 1] + hl * TSF + wb;                           \
    const float* vb_ = vS[(I) & 1] + hl * TSF + wb;                           \
    float v0, v1, v2, v3, v4, v5;                                             \
    LDROW(eb_);                                                               \
    float c0 = v0, c1 = v1, c2 = v2, c3 = v3, c4 = v4, c5 = v5;               \
    float d0 = -v0, d1 = -v1, d2 = -v2, d3 = -v3, d4 = -v4, d5 = -v5;         \
    LDROW(eb_ + TSF);                                                         \
    c0 += v0; c1 += v1; c2 += v2; c3 += v3; c4 += v4; c5 += v5;               \
    LDROW(eb_ + 2 * TSF);                                                     \
    c0 += v0; c1 += v1; c2 += v2; c3 += v3; c4 += v4; c5 += v5;               \
    d0 += v0; d1 += v1; d2 += v2; d3 += v3; d4 += v4; d5 += v5;               \
    LDROW(vb_);                                                               \
    float g0 = v0, g1 = v1, g2 = v2, g3 = v3, g4 = v4, g5 = v5;               \
    LDROW(vb_ + TSF);                                                         \
    g0 += v0; g1 += v1; g2 += v2; g3 += v3; g4 += v4; g5 += v5;               \
    LDROW(vb_ + 2 * TSF);                                                     \
    g0 += v0; g1 += v1; g2 += v2; g3 += v3; g4 += v4; g5 += v5;               \
    s2[SC][0] = c0 + c1 + c2;  s2[SC][1] = c1 + c2 + c3;                      \
    s2[SC][2] = c2 + c3 + c4;  s2[SC][3] = c3 + c4 + c5;                      \
    mx2[SC][0] = c2 - c0; mx2[SC][1] = c3 - c1;                               \
    mx2[SC][2] = c4 - c2; mx2[SC][3] = c5 - c3;                               \
    my2[SC][0] = d0 + d1 + d2;  my2[SC][1] = d1 + d2 + d3;                    \
    my2[SC][2] = d2 + d3 + d4;  my2[SC][3] = d3 + d4 + d5;                    \
    sv2[SC][0] = g0 + g1 + g2;  sv2[SC][1] = g1 + g2 + g3;                    \
    sv2[SC][2] = g2 + g3 + g4;  sv2[SC][3] = g3 + g4 + g5;                    \
} while (0)

// Emit output depth dout = I-2 combining ring slots SA (d-1), SB (d), SC (d+1).
// Nontemporal stores: proven +90us faster than cached (round 3 differential).
#define EMIT(I, SA, SB, SC) do {                                              \
    const int dout_ = (I) - 2;                                                \
    vf4 oz, ox, oy, ov;                                                       \
    _Pragma("unroll")                                                         \
    for (int k = 0; k < 4; ++k) {                                             \
        float S  = s2[SA][k] + s2[SB][k] + s2[SC][k];                         \
        float Mz = s2[SC][k] - s2[SA][k];                                     \
        float Mx = mx2[SA][k] + mx2[SB][k] + mx2[SC][k];                      \
        float My = my2[SA][k] + my2[SB][k] + my2[SC][k];                      \
        float Sv = sv2[SA][k] + sv2[SB][k] + sv2[SC][k];                      \
        float inv = __builtin_amdgcn_rcpf(S + 1e-8f);                         \
        oz[k] = Mz * inv + (float)dout_;                                      \
        ox[k] = Mx * inv + (float)(w0 + wb + k);                              \
        oy[k] = My * inv + (float)(h0 + hl);                                  \
        ov[k] = Sv * inv;                                                     \
    }                                                                         \
    size_t off_ = (size_t)dout_ * PLANE + (size_t)(h0 + hl) * WW + (w0 + wb); \
    __builtin_nontemporal_store(oz, (vf4*)(outz + off_));                     \
    __builtin_nontemporal_store(ox, (vf4*)(outx + off_));                     \
    __builtin_nontemporal_store(oy, (vf4*)(outy + off_));                     \
    __builtin_nontemporal_store(ov, (vf4*)(outv + off_));                     \
} while (0)

// Double-buffer hazard (1 barrier/step): STAGE(I) writes buf[I&1]; stragglers are
// at most in CSLICE(I-1) on the other buffer; CSLICE(I-2) readers of buf[I&1]
// passed the step-(I-1) barrier.
#define STEP(I, SC, SA, SB) do {                                              \
    STAGE(I);                                                                 \
    __syncthreads();                                                          \
    CSLICE(I, SC);                                                            \
    if ((I) >= 2) EMIT(I, SA, SB, SC);                                        \
} while (0)

    for (int ii = 0; ii < 18; ii += 3) {
        STEP(ii + 0, 0, 1, 2);
        STEP(ii + 1, 1, 2, 0);
        STEP(ii + 2, 2, 0, 1);
    }
}

extern "C" void kernel_launch(void* const* d_in, const int* in_sizes, int n_in,
                              void* d_out, int out_size, void* d_ws, size_t ws_size,
                              hipStream_t stream) {
    const float* x = (const float*)d_in[0];
    float* out = (float*)d_out;
    float* part = (float*)d_ws;      // 2048 floats
    float* mx = part + 2048;         // 32 floats

    chmax_part<<<dim3(64, 32), 256, 0, stream>>>(x, part);
    chmax_final<<<32, 64, 0, stream>>>(part, mx);
    csam3d_main<<<dim3(4, 16, 32), 256, 0, stream>>>(x, mx, out);
}